// Round 11
// baseline (498.810 us; speedup 1.0000x reference)
//
#include <hip/hip_runtime.h>

typedef __attribute__((ext_vector_type(8))) short short8;
typedef __attribute__((ext_vector_type(4))) short short4v;
typedef __attribute__((ext_vector_type(4))) float f32x4;

__device__ inline short f2bf(float f) {
    union { float f; unsigned u; } v; v.f = f;
    unsigned r = v.u + 0x7fffu + ((v.u >> 16) & 1u);
    return (short)(r >> 16);
}

__device__ __forceinline__ void gload16(const short* g, short* l) {
    __builtin_amdgcn_global_load_lds(
        (const __attribute__((address_space(1))) unsigned int*)g,
        (__attribute__((address_space(3))) unsigned int*)l, 16, 0, 0);
}

// ---------------- elementwise f32 -> bf16 ----------------
__global__ __launch_bounds__(256) void cvt_f32_to_bf16(const float* __restrict__ in,
                                                       short* __restrict__ out, int n4) {
    int i = blockIdx.x * 256 + threadIdx.x;
    if (i >= n4) return;
    float4 v = ((const float4*)in)[i];
    short4v o;
    o[0] = f2bf(v.x); o[1] = f2bf(v.y); o[2] = f2bf(v.z); o[3] = f2bf(v.w);
    ((short4v*)out)[i] = o;
}

// ---------------- tiled transpose (R x C) f32 -> bf16 (C x R) ----------------
__global__ __launch_bounds__(256) void transpose_to_bf16(const float* __restrict__ in,
                                                         short* __restrict__ out,
                                                         int R, int C) {
    __shared__ short tile[64][66];
    int r0 = blockIdx.x * 64, c0 = blockIdx.y * 64;
    int tid = threadIdx.x;
#pragma unroll
    for (int i = 0; i < 16; i++) {
        int idx = i * 256 + tid;
        int r = idx >> 6, c = idx & 63;
        tile[r][c] = f2bf(in[(size_t)(r0 + r) * C + (c0 + c)]);
    }
    __syncthreads();
#pragma unroll
    for (int i = 0; i < 16; i++) {
        int idx = i * 256 + tid;
        int c = idx >> 6, r = idx & 63;
        out[(size_t)(c0 + c) * R + (r0 + r)] = tile[r][c];
    }
}

// ---------------- bf16 GEMM 128x128, BK=64, SINGLE-buffer (m97 structure) ----------------
// C(MxN) = A(MxK) * Bt(NxK)^T. 256 thr = 4 waves (2x2); per-wave 64x64 out.
// LDS 32KB -> 4 blocks/CU (16 waves): independent blocks' barrier phases
// interleave, hiding stage latency via TLP (m97/m103: 874-912 TF measured).
// Per tile: stage(t) -> __syncthreads (drain) -> 16 ds_read + 32 MFMA -> __syncthreads (WAR).
// LDS rows 128B, chunk slot g^(row&7): 0 bank conflicts (r4/r6/r8/r9).
// Block mapping: XCD x (= bid%8) owns 8-mt band, traversed column-major ->
// co-resident blocks form a tile square per XCD (FETCH 774->197MB, r9).
template <int EPI>
__global__ __launch_bounds__(256) void gemm_bt(const short* __restrict__ A,
                                               const short* __restrict__ Bt,
                                               int M, int N, int K,
                                               short* __restrict__ O0, short* __restrict__ O1,
                                               short* __restrict__ O2, float* __restrict__ OF,
                                               float qscale) {
    __shared__ short Als[128 * 64];
    __shared__ short Bls[128 * 64];
    int tid = threadIdx.x;
    int lane = tid & 63, wid = tid >> 6;
    int wr = wid >> 1, wc = wid & 1;
    int bid = blockIdx.x;
    int xcd = bid & 7;
    int k = bid >> 3;
    int nt = k >> 3;           // column within band
    int gm = k & 7;            // row within band
    int mt = (xcd << 3) + gm;
    int row0 = mt << 7, col0 = nt << 7;
    int t15 = lane & 15, t4 = lane >> 4;
    int lrow = lane >> 3;
    int schunk = (lane & 7) ^ lrow;   // pre-inverse-swizzled global 16B chunk

    f32x4 acc[4][4];
#pragma unroll
    for (int m = 0; m < 4; m++)
#pragma unroll
        for (int n = 0; n < 4; n++) acc[m][n] = (f32x4){0.f, 0.f, 0.f, 0.f};

    int NT = K >> 6;

    auto stage = [&](int t) {
        int k0 = t << 6;
#pragma unroll
        for (int i = 0; i < 4; i++) {
            int seg = wid * 4 + i;        // 16 segs x 8 rows
            int row = seg * 8 + lrow;
            gload16(A + (size_t)(row0 + row) * K + k0 + schunk * 8, &Als[seg * 512]);
            gload16(Bt + (size_t)(col0 + row) * K + k0 + schunk * 8, &Bls[seg * 512]);
        }
    };

    for (int t = 0; t < NT; t++) {
        stage(t);
        __syncthreads();                 // drain: tile t staged & visible

#pragma unroll
        for (int ks = 0; ks < 2; ks++) {
            short8 af[4], bfr[4];
#pragma unroll
            for (int m = 0; m < 4; m++) {
                int row = wr * 64 + m * 16 + t15;
                int ck = (ks * 4 + t4) ^ (row & 7);
                af[m] = *(short8*)(&Als[row * 64 + ck * 8]);
            }
#pragma unroll
            for (int n = 0; n < 4; n++) {
                int row = wc * 64 + n * 16 + t15;
                int ck = (ks * 4 + t4) ^ (row & 7);
                bfr[n] = *(short8*)(&Bls[row * 64 + ck * 8]);
            }
#pragma unroll
            for (int m = 0; m < 4; m++)
#pragma unroll
                for (int n = 0; n < 4; n++)
                    acc[m][n] = __builtin_amdgcn_mfma_f32_16x16x32_bf16(af[m], bfr[n], acc[m][n], 0, 0, 0);
        }

        __syncthreads();                 // WAR: reads done before next stage overwrites
    }

#pragma unroll
    for (int m = 0; m < 4; m++) {
#pragma unroll
        for (int n = 0; n < 4; n++) {
#pragma unroll
            for (int r = 0; r < 4; r++) {
                float v = acc[m][n][r];
                int gm2 = row0 + wr * 64 + m * 16 + t4 * 4 + r;
                int gn = col0 + wc * 64 + n * 16 + t15;
                if (EPI == 0) {
                    int part = gn >> 11, within = gn & 2047;
                    int h = within >> 7, dk = within & 127;
                    int bb = gm2 >> 11, s = gm2 & 2047;
                    int z = bb * 16 + h;
                    if (part == 0) O0[((size_t)z * 2048 + s) * 128 + dk] = f2bf(v * qscale);
                    else if (part == 1) O1[((size_t)z * 2048 + s) * 128 + dk] = f2bf(v);
                    else O2[((size_t)z * 128 + dk) * 2048 + s] = f2bf(v);  // V transposed
                } else {
                    OF[(size_t)gm2 * N + gn] = v;
                }
            }
        }
    }
}

// ---------------- causal flash attention (LDS-staged, paired-panel balanced) ----------------
__global__ __launch_bounds__(512, 4) void attn_fwd(const short* __restrict__ Q,
                                                   const short* __restrict__ Kb,
                                                   const short* __restrict__ Vt,
                                                   short* __restrict__ O) {
    __shared__ short Kls[2][64 * 128];
    __shared__ short Vls[128 * 64];
    __shared__ short Pls[8][16 * 72];
    int tid = threadIdx.x, lane = tid & 63, wid = tid >> 6;
    int bx = blockIdx.x, z = blockIdx.y;
    int pr = bx >> 1, hh = bx & 1;
    int qpan = (wid < 4) ? pr : (15 - pr);
    int t15 = lane & 15, t4 = lane >> 4;
    const short* Qh = Q + (size_t)z * 2048 * 128;
    const short* Kh = Kb + (size_t)z * 2048 * 128;
    const short* Vh = Vt + (size_t)z * 128 * 2048;
    int q0w = qpan * 128 + hh * 64 + (wid & 3) * 16;

    short8 qf[4];
    {
        const short* qrow = Qh + (size_t)(q0w + t15) * 128;
#pragma unroll
        for (int s = 0; s < 4; s++) qf[s] = *(const short8*)(qrow + s * 32 + t4 * 8);
    }

    f32x4 o[8];
#pragma unroll
    for (int st = 0; st < 8; st++) o[st] = (f32x4){0.f, 0.f, 0.f, 0.f};
    float m_r[4], l_r[4];
#pragma unroll
    for (int r = 0; r < 4; r++) { m_r[r] = -1e30f; l_r[r] = 0.f; }

    auto stageK = [&](int t, int buf) {
#pragma unroll
        for (int i = 0; i < 2; i++) {
            int seg = wid * 2 + i;
            int row = seg * 4 + t4;
            int kl = (lane & 15) ^ (row & 7);
            gload16(Kh + (size_t)(t * 64 + row) * 128 + kl * 8, &Kls[buf][seg * 512]);
        }
    };
    auto stageV = [&](int t) {
#pragma unroll
        for (int i = 0; i < 2; i++) {
            int seg = wid * 2 + i;
            int row = seg * 8 + (lane >> 3);
            int kl = (lane & 7) ^ (row & 7);
            gload16(Vh + (size_t)row * 2048 + t * 64 + kl * 8, &Vls[seg * 512]);
        }
    };

    int nt = 2 * (15 - pr) + 2;
    stageK(0, 0);
    __syncthreads();

    for (int t = 0; t < nt; t++) {
        int buf = t & 1;
        stageV(t);                                  // consumed after barrier1
        if (t + 1 < nt) stageK(t + 1, buf ^ 1);     // consumed next iter
        bool active = (t * 64 <= q0w + 15);

        if (active) {
            f32x4 sc[4];
#pragma unroll
            for (int c = 0; c < 4; c++) {
                sc[c] = (f32x4){0.f, 0.f, 0.f, 0.f};
#pragma unroll
                for (int s = 0; s < 4; s++) {
                    int row = c * 16 + t15;
                    int ck = (s * 4 + t4) ^ (row & 7);
                    short8 kf = *(short8*)(&Kls[buf][row * 128 + ck * 8]);
                    sc[c] = __builtin_amdgcn_mfma_f32_16x16x32_bf16(qf[s], kf, sc[c], 0, 0, 0);
                }
            }

            if (t * 64 + 63 > q0w) {
#pragma unroll
                for (int c = 0; c < 4; c++)
#pragma unroll
                    for (int r = 0; r < 4; r++) {
                        int kv = t * 64 + c * 16 + t15, qq = q0w + t4 * 4 + r;
                        if (kv > qq) sc[c][r] = -1e30f;
                    }
            }

            float tm[4];
#pragma unroll
            for (int r = 0; r < 4; r++)
                tm[r] = fmaxf(fmaxf(sc[0][r], sc[1][r]), fmaxf(sc[2][r], sc[3][r]));
            bool need = (tm[0] > m_r[0] + 8.f) | (tm[1] > m_r[1] + 8.f) |
                        (tm[2] > m_r[2] + 8.f) | (tm[3] > m_r[3] + 8.f);
            if (__any(need)) {
#pragma unroll
                for (int r = 0; r < 4; r++) {
#pragma unroll
                    for (int msk = 1; msk <= 8; msk <<= 1)
                        tm[r] = fmaxf(tm[r], __shfl_xor(tm[r], msk));
                    float mn = fmaxf(m_r[r], tm[r]);
                    float scf = __expf(m_r[r] - mn);
                    m_r[r] = mn;
                    l_r[r] *= scf;
#pragma unroll
                    for (int st = 0; st < 8; st++) o[st][r] *= scf;
                }
            }
#pragma unroll
            for (int r = 0; r < 4; r++) {
#pragma unroll
                for (int c = 0; c < 4; c++) {
                    float pv = __expf(sc[c][r] - m_r[r]);
                    Pls[wid][(t4 * 4 + r) * 72 + c * 16 + t15] = f2bf(pv);
                    l_r[r] += pv;
                }
            }
        }

        __syncthreads();   // barrier1: V(t) and K(t+1) staged & visible

        if (active) {
            short8 pa[2];
#pragma unroll
            for (int s2 = 0; s2 < 2; s2++)
                pa[s2] = *(short8*)(&Pls[wid][0] + t15 * 72 + s2 * 32 + t4 * 8);
#pragma unroll
            for (int st = 0; st < 8; st++) {
#pragma unroll
                for (int s2 = 0; s2 < 2; s2++) {
                    int row = st * 16 + t15;
                    int ck = (s2 * 4 + t4) ^ (row & 7);
                    short8 vf = *(short8*)(&Vls[row * 64 + ck * 8]);
                    o[st] = __builtin_amdgcn_mfma_f32_16x16x32_bf16(pa[s2], vf, o[st], 0, 0, 0);
                }
            }
        }

        __syncthreads();   // barrier2: WAR for Vls / Kls[buf]
    }

#pragma unroll
    for (int r = 0; r < 4; r++)
#pragma unroll
        for (int msk = 1; msk <= 8; msk <<= 1)
            l_r[r] += __shfl_xor(l_r[r], msk);

    int b = z >> 4, h = z & 15;
#pragma unroll
    for (int st = 0; st < 8; st++)
#pragma unroll
        for (int r = 0; r < 4; r++) {
            int s = q0w + t4 * 4 + r;
            float val = o[st][r] / l_r[r];
            O[((size_t)b * 2048 + s) * 2048 + h * 128 + st * 16 + t15] = f2bf(val);
        }
}

extern "C" void kernel_launch(void* const* d_in, const int* in_sizes, int n_in,
                              void* d_out, int out_size, void* d_ws, size_t ws_size,
                              hipStream_t stream) {
    const float* x = (const float*)d_in[0];      // (4,2048,2048)
    const float* Wqkv = (const float*)d_in[1];   // (2048,6144)
    const float* Wo = (const float*)d_in[2];     // (2048,2048)

    const int B = 4, S = 2048, D = 2048, DK = 128;
    const int M = B * S;          // 8192
    const int N1 = 3 * D;         // 6144
    (void)in_sizes; (void)n_in; (void)out_size; (void)ws_size;

    char* ws = (char*)d_ws;
    size_t off = 0;
    short* x_bf = (short*)(ws + off);   off += (size_t)M * D * 2;
    short* wqkv_t = (short*)(ws + off); off += (size_t)N1 * D * 2;
    short* wo_t = (short*)(ws + off);   off += (size_t)D * D * 2;
    short* Qb = (short*)(ws + off);     off += (size_t)64 * S * DK * 2;
    short* Kb = (short*)(ws + off);     off += (size_t)64 * S * DK * 2;
    short* Vt = (short*)(ws + off);     off += (size_t)64 * S * DK * 2;
    short* Ob = (short*)(ws + off);     off += (size_t)M * D * 2;

    // 1. x -> bf16
    cvt_f32_to_bf16<<<(M * D / 4 + 255) / 256, 256, 0, stream>>>(x, x_bf, M * D / 4);
    // 2. Wqkv^T -> bf16 (N1 x D)
    transpose_to_bf16<<<dim3(D / 64, N1 / 64, 1), 256, 0, stream>>>(Wqkv, wqkv_t, D, N1);
    // 3. Wo^T -> bf16 (D x D)
    transpose_to_bf16<<<dim3(D / 64, D / 64, 1), 256, 0, stream>>>(Wo, wo_t, D, D);
    // 4. GEMM1: qkv = x @ Wqkv -> Q(scaled)/K/V^T   (128x128, 3072 blocks, banded, 4/CU)
    gemm_bt<0><<<(M / 128) * (N1 / 128), 256, 0, stream>>>(
        x_bf, wqkv_t, M, N1, D, Qb, Kb, Vt, nullptr, 0.08838834764831845f);
    // 5. attention (paired-panel balanced, hoisted prefetch)
    attn_fwd<<<dim3(16, 64), 512, 0, stream>>>(Qb, Kb, Vt, Ob);
    // 6. GEMM2: out = O @ Wo (f32)                  (128x128, 1024 blocks, banded, 4/CU)
    gemm_bt<1><<<(M / 128) * (D / 128), 256, 0, stream>>>(
        Ob, wo_t, M, D, D, nullptr, nullptr, nullptr, (float*)d_out, 1.0f);
}

// Round 12
// 460.461 us; speedup vs baseline: 1.0833x; 1.0833x over previous
//
#include <hip/hip_runtime.h>

typedef __attribute__((ext_vector_type(8))) short short8;
typedef __attribute__((ext_vector_type(4))) short short4v;
typedef __attribute__((ext_vector_type(4))) float f32x4;

__device__ inline short f2bf(float f) {
    union { float f; unsigned u; } v; v.f = f;
    unsigned r = v.u + 0x7fffu + ((v.u >> 16) & 1u);
    return (short)(r >> 16);
}

__device__ __forceinline__ void gload16(const short* g, short* l) {
    __builtin_amdgcn_global_load_lds(
        (const __attribute__((address_space(1))) unsigned int*)g,
        (__attribute__((address_space(3))) unsigned int*)l, 16, 0, 0);
}

// ---------------- elementwise f32 -> bf16 ----------------
__global__ __launch_bounds__(256) void cvt_f32_to_bf16(const float* __restrict__ in,
                                                       short* __restrict__ out, int n4) {
    int i = blockIdx.x * 256 + threadIdx.x;
    if (i >= n4) return;
    float4 v = ((const float4*)in)[i];
    short4v o;
    o[0] = f2bf(v.x); o[1] = f2bf(v.y); o[2] = f2bf(v.z); o[3] = f2bf(v.w);
    ((short4v*)out)[i] = o;
}

// ---------------- tiled transpose (R x C) f32 -> bf16 (C x R) ----------------
__global__ __launch_bounds__(256) void transpose_to_bf16(const float* __restrict__ in,
                                                         short* __restrict__ out,
                                                         int R, int C) {
    __shared__ short tile[64][66];
    int r0 = blockIdx.x * 64, c0 = blockIdx.y * 64;
    int tid = threadIdx.x;
#pragma unroll
    for (int i = 0; i < 16; i++) {
        int idx = i * 256 + tid;
        int r = idx >> 6, c = idx & 63;
        tile[r][c] = f2bf(in[(size_t)(r0 + r) * C + (c0 + c)]);
    }
    __syncthreads();
#pragma unroll
    for (int i = 0; i < 16; i++) {
        int idx = i * 256 + tid;
        int c = idx >> 6, r = idx & 63;
        out[(size_t)(c0 + c) * R + (r0 + r)] = tile[r][c];
    }
}

// ======== bf16 GEMM 256x256, BK=64 as 2x K-half(32), 8-phase pipeline (m201-style) ====
// 512 thr = 8 waves (2M x 4N); per-wave 128x64 out; acc 8x4 f32x4 (128 VGPR).
// LDS 128KB: As/Bs[2 dbuf][2 khalf][256 rows x 32 cols], rows 64B, chunk stored at
// cpos = g ^ ((row>>1)&3)  (r6-verified 0-conflict scheme).
// Group (K-tile t, dbuf d=t&1), 4 phases: (kh0,np0)(kh0,np1)(kh1,np0)(kh1,np1);
// per phase: ds_read frags -> stage one half-tile -> barrier -> lgkm(0)+schedbar ->
// setprio(1) 16 MFMA setprio(0) -> [vmcnt at odd phases] -> barrier.
// Stage schedule in group t: p0:A-kh1(t+1) p1:B-kh1(t+1) p2:A-kh0(t+2) p3:B-kh0(t+2).
// Every half staged >=4 phases before first read; slots rewritten >=1 barrier after
// last read; vmcnt(8) keeps 4 stages (8 loads) in flight (never drains mid-loop).
template <int EPI>
__global__ __launch_bounds__(512) void gemm256(const short* __restrict__ A,
                                               const short* __restrict__ Bt,
                                               int M, int N, int K,
                                               short* __restrict__ O0, short* __restrict__ O1,
                                               short* __restrict__ O2, float* __restrict__ OF,
                                               float qscale) {
    __shared__ short As[2][2][256 * 32];
    __shared__ short Bs[2][2][256 * 32];
    int tid = threadIdx.x, lane = tid & 63, wid = tid >> 6;
    int wr = wid >> 2, wc = wid & 3;
    int mtn = M >> 8, ntn = N >> 8; (void)ntn;
    int band = mtn >> 3;                 // band rows per XCD
    int bid = blockIdx.x;
    int xcd = bid & 7, kk = bid >> 3;
    int nt = kk / band, gmr = kk % band; // column-major within band (r9 L2 win)
    int mt = xcd * band + gmr;
    int row0 = mt << 8, col0 = nt << 8;
    int t15 = lane & 15, t4 = lane >> 4;
    int NT = K >> 6;

    f32x4 acc[8][4];
#pragma unroll
    for (int m = 0; m < 8; m++)
#pragma unroll
        for (int n = 0; n < 4; n++) acc[m][n] = (f32x4){0.f, 0.f, 0.f, 0.f};

    int sg = (lane & 3) ^ ((lane >> 3) & 3);   // staging global chunk (inverse swizzle)
    int srw = lane >> 2;                       // staging row within 16-row seg
    int ce = t4 ^ ((t15 >> 1) & 3);            // read-side swizzled chunk

    auto stageA = [&](int t, int kh) {
        if (t >= NT) return;
        int kb = (t << 6) + (kh << 5);
        short* dst = &As[t & 1][kh][0];
#pragma unroll
        for (int i = 0; i < 2; i++) {
            int seg = wid * 2 + i;
            int row = seg * 16 + srw;
            gload16(A + (size_t)(row0 + row) * K + kb + sg * 8, dst + seg * 512);
        }
    };
    auto stageB = [&](int t, int kh) {
        if (t >= NT) return;
        int kb = (t << 6) + (kh << 5);
        short* dst = &Bs[t & 1][kh][0];
#pragma unroll
        for (int i = 0; i < 2; i++) {
            int seg = wid * 2 + i;
            int row = seg * 16 + srw;
            gload16(Bt + (size_t)(col0 + row) * K + kb + sg * 8, dst + seg * 512);
        }
    };

    short8 af[8], bf[2];
    auto lda = [&](int d, int kh) {
#pragma unroll
        for (int m = 0; m < 8; m++) {
            int row = wr * 128 + m * 16 + t15;
            af[m] = *(short8*)(&As[d][kh][row * 32 + ce * 8]);
        }
    };
    auto ldb = [&](int d, int kh, int np) {
#pragma unroll
        for (int j = 0; j < 2; j++) {
            int row = wc * 64 + (np * 2 + j) * 16 + t15;
            bf[j] = *(short8*)(&Bs[d][kh][row * 32 + ce * 8]);
        }
    };

#define MFMA16(NP)                                                                   \
    __builtin_amdgcn_s_setprio(1);                                                   \
    _Pragma("unroll")                                                                \
    for (int m_ = 0; m_ < 8; m_++) {                                                 \
        acc[m_][(NP)*2 + 0] = __builtin_amdgcn_mfma_f32_16x16x32_bf16(               \
            af[m_], bf[0], acc[m_][(NP)*2 + 0], 0, 0, 0);                            \
        acc[m_][(NP)*2 + 1] = __builtin_amdgcn_mfma_f32_16x16x32_bf16(               \
            af[m_], bf[1], acc[m_][(NP)*2 + 1], 0, 0, 0);                            \
    }                                                                                \
    __builtin_amdgcn_s_setprio(0);

#define BARR asm volatile("s_barrier" ::: "memory")
#define LGKM0 do { asm volatile("s_waitcnt lgkmcnt(0)" ::: "memory");                \
                   __builtin_amdgcn_sched_barrier(0); } while (0)

    // prologue: virtual stage order A0(0) B0(0) A1(0) B1(0) A0(1) B0(1)
    stageA(0, 0); stageB(0, 0);
    stageA(0, 1); stageB(0, 1);
    stageA(1, 0); stageB(1, 0);
    if (NT >= 2) asm volatile("s_waitcnt vmcnt(8)" ::: "memory");
    else         asm volatile("s_waitcnt vmcnt(4)" ::: "memory");
    BARR;

    for (int t = 0; t < NT; t++) {
        int d = t & 1;
        // phase 0: (kh0, np0); stage A-kh1(t+1)
        lda(d, 0); ldb(d, 0, 0);
        stageA(t + 1, 1);
        BARR; LGKM0;
        MFMA16(0);
        BARR;
        // phase 1: (kh0, np1); stage B-kh1(t+1); wait1
        ldb(d, 0, 1);
        stageB(t + 1, 1);
        BARR; LGKM0;
        MFMA16(1);
        if (t + 1 < NT) asm volatile("s_waitcnt vmcnt(8)" ::: "memory");
        else            asm volatile("s_waitcnt vmcnt(0)" ::: "memory");
        BARR;
        // phase 2: (kh1, np0); stage A-kh0(t+2)
        lda(d, 1); ldb(d, 1, 0);
        stageA(t + 2, 0);
        BARR; LGKM0;
        MFMA16(0);
        BARR;
        // phase 3: (kh1, np1); stage B-kh0(t+2); wait2
        ldb(d, 1, 1);
        stageB(t + 2, 0);
        BARR; LGKM0;
        MFMA16(1);
        if (t + 2 < NT)      asm volatile("s_waitcnt vmcnt(8)" ::: "memory");
        else if (t + 1 < NT) asm volatile("s_waitcnt vmcnt(4)" ::: "memory");
        else                 asm volatile("s_waitcnt vmcnt(0)" ::: "memory");
        BARR;
    }

#undef MFMA16
#undef BARR
#undef LGKM0

#pragma unroll
    for (int m = 0; m < 8; m++) {
#pragma unroll
        for (int n = 0; n < 4; n++) {
#pragma unroll
            for (int r = 0; r < 4; r++) {
                float v = acc[m][n][r];
                int gm2 = row0 + wr * 128 + m * 16 + t4 * 4 + r;
                int gn = col0 + wc * 64 + n * 16 + t15;
                if (EPI == 0) {
                    int part = gn >> 11, within = gn & 2047;
                    int h = within >> 7, dk = within & 127;
                    int bb = gm2 >> 11, s = gm2 & 2047;
                    int z = bb * 16 + h;
                    if (part == 0) O0[((size_t)z * 2048 + s) * 128 + dk] = f2bf(v * qscale);
                    else if (part == 1) O1[((size_t)z * 2048 + s) * 128 + dk] = f2bf(v);
                    else O2[((size_t)z * 128 + dk) * 2048 + s] = f2bf(v);  // V transposed
                } else {
                    OF[(size_t)gm2 * N + gn] = v;
                }
            }
        }
    }
}

// ---------------- bf16 GEMM 128x128, BK=64, 2-buf counted-vmcnt (r10, for GEMM2) ----
template <int EPI>
__global__ __launch_bounds__(256) void gemm_bt(const short* __restrict__ A,
                                               const short* __restrict__ Bt,
                                               int M, int N, int K,
                                               short* __restrict__ O0, short* __restrict__ O1,
                                               short* __restrict__ O2, float* __restrict__ OF,
                                               float qscale) {
    __shared__ short Als[2][128 * 64];
    __shared__ short Bls[2][128 * 64];
    int tid = threadIdx.x;
    int lane = tid & 63, wid = tid >> 6;
    int wr = wid >> 1, wc = wid & 1;
    int bid = blockIdx.x;
    int xcd = bid & 7;
    int k = bid >> 3;
    int nt = k >> 3;
    int gm = k & 7;
    int mt = (xcd << 3) + gm;
    int row0 = mt << 7, col0 = nt << 7;
    int t15 = lane & 15, t4 = lane >> 4;
    int lrow = lane >> 3;
    int schunk = (lane & 7) ^ lrow;

    f32x4 acc[4][4];
#pragma unroll
    for (int m = 0; m < 4; m++)
#pragma unroll
        for (int n = 0; n < 4; n++) acc[m][n] = (f32x4){0.f, 0.f, 0.f, 0.f};

    int NT = K >> 6;

    auto stage = [&](int t, int b) {
        int k0 = t << 6;
#pragma unroll
        for (int i = 0; i < 4; i++) {
            int seg = wid * 4 + i;
            int row = seg * 8 + lrow;
            gload16(A + (size_t)(row0 + row) * K + k0 + schunk * 8, &Als[b][seg * 512]);
            gload16(Bt + (size_t)(col0 + row) * K + k0 + schunk * 8, &Bls[b][seg * 512]);
        }
    };

    stage(0, 0);

    for (int t = 0; t < NT; t++) {
        int b = t & 1;
        if (t + 1 < NT) {
            stage(t + 1, b ^ 1);
            asm volatile("s_waitcnt vmcnt(8)" ::: "memory");
        } else {
            asm volatile("s_waitcnt vmcnt(0)" ::: "memory");
        }
        __builtin_amdgcn_s_barrier();
        __builtin_amdgcn_sched_barrier(0);

#pragma unroll
        for (int ks = 0; ks < 2; ks++) {
            short8 af[4], bfr[4];
#pragma unroll
            for (int m = 0; m < 4; m++) {
                int row = wr * 64 + m * 16 + t15;
                int ck = (ks * 4 + t4) ^ (row & 7);
                af[m] = *(short8*)(&Als[b][row * 64 + ck * 8]);
            }
#pragma unroll
            for (int n = 0; n < 4; n++) {
                int row = wc * 64 + n * 16 + t15;
                int ck = (ks * 4 + t4) ^ (row & 7);
                bfr[n] = *(short8*)(&Bls[b][row * 64 + ck * 8]);
            }
#pragma unroll
            for (int m = 0; m < 4; m++)
#pragma unroll
                for (int n = 0; n < 4; n++)
                    acc[m][n] = __builtin_amdgcn_mfma_f32_16x16x32_bf16(af[m], bfr[n], acc[m][n], 0, 0, 0);
        }

        __builtin_amdgcn_s_barrier();
        __builtin_amdgcn_sched_barrier(0);
    }

#pragma unroll
    for (int m = 0; m < 4; m++) {
#pragma unroll
        for (int n = 0; n < 4; n++) {
#pragma unroll
            for (int r = 0; r < 4; r++) {
                float v = acc[m][n][r];
                int gm2 = row0 + wr * 64 + m * 16 + t4 * 4 + r;
                int gn = col0 + wc * 64 + n * 16 + t15;
                if (EPI == 0) {
                    int part = gn >> 11, within = gn & 2047;
                    int h = within >> 7, dk = within & 127;
                    int bb = gm2 >> 11, s = gm2 & 2047;
                    int z = bb * 16 + h;
                    if (part == 0) O0[((size_t)z * 2048 + s) * 128 + dk] = f2bf(v * qscale);
                    else if (part == 1) O1[((size_t)z * 2048 + s) * 128 + dk] = f2bf(v);
                    else O2[((size_t)z * 128 + dk) * 2048 + s] = f2bf(v);
                } else {
                    OF[(size_t)gm2 * N + gn] = v;
                }
            }
        }
    }
}

// ---------------- causal flash attention (LDS-staged, paired-panel balanced) ----------------
__global__ __launch_bounds__(512, 4) void attn_fwd(const short* __restrict__ Q,
                                                   const short* __restrict__ Kb,
                                                   const short* __restrict__ Vt,
                                                   short* __restrict__ O) {
    __shared__ short Kls[2][64 * 128];
    __shared__ short Vls[128 * 64];
    __shared__ short Pls[8][16 * 72];
    int tid = threadIdx.x, lane = tid & 63, wid = tid >> 6;
    int bx = blockIdx.x, z = blockIdx.y;
    int pr = bx >> 1, hh = bx & 1;
    int qpan = (wid < 4) ? pr : (15 - pr);
    int t15 = lane & 15, t4 = lane >> 4;
    const short* Qh = Q + (size_t)z * 2048 * 128;
    const short* Kh = Kb + (size_t)z * 2048 * 128;
    const short* Vh = Vt + (size_t)z * 128 * 2048;
    int q0w = qpan * 128 + hh * 64 + (wid & 3) * 16;

    short8 qf[4];
    {
        const short* qrow = Qh + (size_t)(q0w + t15) * 128;
#pragma unroll
        for (int s = 0; s < 4; s++) qf[s] = *(const short8*)(qrow + s * 32 + t4 * 8);
    }

    f32x4 o[8];
#pragma unroll
    for (int st = 0; st < 8; st++) o[st] = (f32x4){0.f, 0.f, 0.f, 0.f};
    float m_r[4], l_r[4];
#pragma unroll
    for (int r = 0; r < 4; r++) { m_r[r] = -1e30f; l_r[r] = 0.f; }

    auto stageK = [&](int t, int buf) {
#pragma unroll
        for (int i = 0; i < 2; i++) {
            int seg = wid * 2 + i;
            int row = seg * 4 + t4;
            int kl = (lane & 15) ^ (row & 7);
            gload16(Kh + (size_t)(t * 64 + row) * 128 + kl * 8, &Kls[buf][seg * 512]);
        }
    };
    auto stageV = [&](int t) {
#pragma unroll
        for (int i = 0; i < 2; i++) {
            int seg = wid * 2 + i;
            int row = seg * 8 + (lane >> 3);
            int kl = (lane & 7) ^ (row & 7);
            gload16(Vh + (size_t)row * 2048 + t * 64 + kl * 8, &Vls[seg * 512]);
        }
    };

    int nt = 2 * (15 - pr) + 2;
    stageK(0, 0);
    __syncthreads();

    for (int t = 0; t < nt; t++) {
        int buf = t & 1;
        stageV(t);
        if (t + 1 < nt) stageK(t + 1, buf ^ 1);
        bool active = (t * 64 <= q0w + 15);

        if (active) {
            f32x4 sc[4];
#pragma unroll
            for (int c = 0; c < 4; c++) {
                sc[c] = (f32x4){0.f, 0.f, 0.f, 0.f};
#pragma unroll
                for (int s = 0; s < 4; s++) {
                    int row = c * 16 + t15;
                    int ck = (s * 4 + t4) ^ (row & 7);
                    short8 kf = *(short8*)(&Kls[buf][row * 128 + ck * 8]);
                    sc[c] = __builtin_amdgcn_mfma_f32_16x16x32_bf16(qf[s], kf, sc[c], 0, 0, 0);
                }
            }

            if (t * 64 + 63 > q0w) {
#pragma unroll
                for (int c = 0; c < 4; c++)
#pragma unroll
                    for (int r = 0; r < 4; r++) {
                        int kv = t * 64 + c * 16 + t15, qq = q0w + t4 * 4 + r;
                        if (kv > qq) sc[c][r] = -1e30f;
                    }
            }

            float tm[4];
#pragma unroll
            for (int r = 0; r < 4; r++)
                tm[r] = fmaxf(fmaxf(sc[0][r], sc[1][r]), fmaxf(sc[2][r], sc[3][r]));
            bool need = (tm[0] > m_r[0] + 8.f) | (tm[1] > m_r[1] + 8.f) |
                        (tm[2] > m_r[2] + 8.f) | (tm[3] > m_r[3] + 8.f);
            if (__any(need)) {
#pragma unroll
                for (int r = 0; r < 4; r++) {
#pragma unroll
                    for (int msk = 1; msk <= 8; msk <<= 1)
                        tm[r] = fmaxf(tm[r], __shfl_xor(tm[r], msk));
                    float mn = fmaxf(m_r[r], tm[r]);
                    float scf = __expf(m_r[r] - mn);
                    m_r[r] = mn;
                    l_r[r] *= scf;
#pragma unroll
                    for (int st = 0; st < 8; st++) o[st][r] *= scf;
                }
            }
#pragma unroll
            for (int r = 0; r < 4; r++) {
#pragma unroll
                for (int c = 0; c < 4; c++) {
                    float pv = __expf(sc[c][r] - m_r[r]);
                    Pls[wid][(t4 * 4 + r) * 72 + c * 16 + t15] = f2bf(pv);
                    l_r[r] += pv;
                }
            }
        }

        __syncthreads();

        if (active) {
            short8 pa[2];
#pragma unroll
            for (int s2 = 0; s2 < 2; s2++)
                pa[s2] = *(short8*)(&Pls[wid][0] + t15 * 72 + s2 * 32 + t4 * 8);
#pragma unroll
            for (int st = 0; st < 8; st++) {
#pragma unroll
                for (int s2 = 0; s2 < 2; s2++) {
                    int row = st * 16 + t15;
                    int ck = (s2 * 4 + t4) ^ (row & 7);
                    short8 vf = *(short8*)(&Vls[row * 64 + ck * 8]);
                    o[st] = __builtin_amdgcn_mfma_f32_16x16x32_bf16(pa[s2], vf, o[st], 0, 0, 0);
                }
            }
        }

        __syncthreads();
    }

#pragma unroll
    for (int r = 0; r < 4; r++)
#pragma unroll
        for (int msk = 1; msk <= 8; msk <<= 1)
            l_r[r] += __shfl_xor(l_r[r], msk);

    int b = z >> 4, h = z & 15;
#pragma unroll
    for (int st = 0; st < 8; st++)
#pragma unroll
        for (int r = 0; r < 4; r++) {
            int s = q0w + t4 * 4 + r;
            float val = o[st][r] / l_r[r];
            O[((size_t)b * 2048 + s) * 2048 + h * 128 + st * 16 + t15] = f2bf(val);
        }
}

extern "C" void kernel_launch(void* const* d_in, const int* in_sizes, int n_in,
                              void* d_out, int out_size, void* d_ws, size_t ws_size,
                              hipStream_t stream) {
    const float* x = (const float*)d_in[0];      // (4,2048,2048)
    const float* Wqkv = (const float*)d_in[1];   // (2048,6144)
    const float* Wo = (const float*)d_in[2];     // (2048,2048)

    const int B = 4, S = 2048, D = 2048, DK = 128;
    const int M = B * S;          // 8192
    const int N1 = 3 * D;         // 6144
    (void)in_sizes; (void)n_in; (void)out_size; (void)ws_size;

    char* ws = (char*)d_ws;
    size_t off = 0;
    short* x_bf = (short*)(ws + off);   off += (size_t)M * D * 2;
    short* wqkv_t = (short*)(ws + off); off += (size_t)N1 * D * 2;
    short* wo_t = (short*)(ws + off);   off += (size_t)D * D * 2;
    short* Qb = (short*)(ws + off);     off += (size_t)64 * S * DK * 2;
    short* Kb = (short*)(ws + off);     off += (size_t)64 * S * DK * 2;
    short* Vt = (short*)(ws + off);     off += (size_t)64 * S * DK * 2;
    short* Ob = (short*)(ws + off);     off += (size_t)M * D * 2;

    // 1. x -> bf16
    cvt_f32_to_bf16<<<(M * D / 4 + 255) / 256, 256, 0, stream>>>(x, x_bf, M * D / 4);
    // 2. Wqkv^T -> bf16 (N1 x D)
    transpose_to_bf16<<<dim3(D / 64, N1 / 64, 1), 256, 0, stream>>>(Wqkv, wqkv_t, D, N1);
    // 3. Wo^T -> bf16 (D x D)
    transpose_to_bf16<<<dim3(D / 64, D / 64, 1), 256, 0, stream>>>(Wo, wo_t, D, D);
    // 4. GEMM1: qkv = x @ Wqkv -> Q(scaled)/K/V^T   (256x256 8-phase, 768 blocks)
    gemm256<0><<<(M / 256) * (N1 / 256), 512, 0, stream>>>(
        x_bf, wqkv_t, M, N1, D, Qb, Kb, Vt, nullptr, 0.08838834764831845f);
    // 5. attention (paired-panel balanced, hoisted prefetch)
    attn_fwd<<<dim3(16, 64), 512, 0, stream>>>(Qb, Kb, Vt, Ob);
    // 6. GEMM2: out = O @ Wo (f32)   (128x128 2-buf counted-vmcnt, 1024 blocks, banded)
    gemm_bt<1><<<(M / 128) * (D / 128), 256, 0, stream>>>(
        Ob, wo_t, M, D, D, nullptr, nullptr, nullptr, (float*)d_out, 1.0f);
}

// Round 13
// 449.267 us; speedup vs baseline: 1.1103x; 1.0249x over previous
//
#include <hip/hip_runtime.h>

typedef __attribute__((ext_vector_type(8))) short short8;
typedef __attribute__((ext_vector_type(4))) short short4v;
typedef __attribute__((ext_vector_type(4))) float f32x4;

__device__ inline short f2bf(float f) {
    union { float f; unsigned u; } v; v.f = f;
    unsigned r = v.u + 0x7fffu + ((v.u >> 16) & 1u);
    return (short)(r >> 16);
}

__device__ __forceinline__ void gload16(const short* g, short* l) {
    __builtin_amdgcn_global_load_lds(
        (const __attribute__((address_space(1))) unsigned int*)g,
        (__attribute__((address_space(3))) unsigned int*)l, 16, 0, 0);
}

// ---------------- elementwise f32 -> bf16 ----------------
__global__ __launch_bounds__(256) void cvt_f32_to_bf16(const float* __restrict__ in,
                                                       short* __restrict__ out, int n4) {
    int i = blockIdx.x * 256 + threadIdx.x;
    if (i >= n4) return;
    float4 v = ((const float4*)in)[i];
    short4v o;
    o[0] = f2bf(v.x); o[1] = f2bf(v.y); o[2] = f2bf(v.z); o[3] = f2bf(v.w);
    ((short4v*)out)[i] = o;
}

// ---------------- tiled transpose (R x C) f32 -> bf16 (C x R) ----------------
__global__ __launch_bounds__(256) void transpose_to_bf16(const float* __restrict__ in,
                                                         short* __restrict__ out,
                                                         int R, int C) {
    __shared__ short tile[64][66];
    int r0 = blockIdx.x * 64, c0 = blockIdx.y * 64;
    int tid = threadIdx.x;
#pragma unroll
    for (int i = 0; i < 16; i++) {
        int idx = i * 256 + tid;
        int r = idx >> 6, c = idx & 63;
        tile[r][c] = f2bf(in[(size_t)(r0 + r) * C + (c0 + c)]);
    }
    __syncthreads();
#pragma unroll
    for (int i = 0; i < 16; i++) {
        int idx = i * 256 + tid;
        int c = idx >> 6, r = idx & 63;
        out[(size_t)(c0 + c) * R + (r0 + r)] = tile[r][c];
    }
}

// ======== bf16 GEMM 256x256, BK=64 as 2x K-half(32), 8-phase pipeline ====
// 512 thr = 8 waves (2M x 4N); per-wave 128x64 out; acc 8x4 f32x4.
// LDS 128KB: As/Bs[2 dbuf][2 khalf][256 x 32], 64B rows, chunk at cpos=g^((row>>1)&3)
// (verified 0 bank conflicts r6/r12). Per phase: ds_read frags -> stage one
// half-tile -> barrier -> [counted vmcnt at odd phases] -> setprio(1) 16 MFMA
// setprio(0) -> barrier. NO lgkmcnt(0)/sched_barrier pins (m141: pinning defeats
// the compiler's own counted-lgkmcnt interleave; deps are register-scoreboarded).
// Visibility ledger: data read at phase p staged >=4 phases earlier and forced
// complete by the vmcnt(8) (12 outstanding -> oldest 4 retired) before the
// barrier preceding the read. WAR: slots rewritten >=1 barrier after last read.
template <int EPI>
__global__ __launch_bounds__(512) void gemm256(const short* __restrict__ A,
                                               const short* __restrict__ Bt,
                                               int M, int N, int K,
                                               short* __restrict__ O0, short* __restrict__ O1,
                                               short* __restrict__ O2, float* __restrict__ OF,
                                               float qscale) {
    __shared__ short As[2][2][256 * 32];
    __shared__ short Bs[2][2][256 * 32];
    int tid = threadIdx.x, lane = tid & 63, wid = tid >> 6;
    int wr = wid >> 2, wc = wid & 3;
    int mtn = M >> 8;
    int band = mtn >> 3;                 // band rows per XCD
    int bid = blockIdx.x;
    int xcd = bid & 7, kk = bid >> 3;
    int nt = kk / band, gmr = kk % band; // column-major within band (r9 L2 win)
    int mt = xcd * band + gmr;
    int row0 = mt << 8, col0 = nt << 8;
    int t15 = lane & 15, t4 = lane >> 4;
    int NT = K >> 6;

    f32x4 acc[8][4];
#pragma unroll
    for (int m = 0; m < 8; m++)
#pragma unroll
        for (int n = 0; n < 4; n++) acc[m][n] = (f32x4){0.f, 0.f, 0.f, 0.f};

    int sg = (lane & 3) ^ ((lane >> 3) & 3);   // staging global chunk (inverse swizzle)
    int srw = lane >> 2;                       // staging row within 16-row seg
    int ce = t4 ^ ((t15 >> 1) & 3);            // read-side swizzled chunk

    auto stageA = [&](int t, int kh) {
        if (t >= NT) return;
        int kb = (t << 6) + (kh << 5);
        short* dst = &As[t & 1][kh][0];
#pragma unroll
        for (int i = 0; i < 2; i++) {
            int seg = wid * 2 + i;
            int row = seg * 16 + srw;
            gload16(A + (size_t)(row0 + row) * K + kb + sg * 8, dst + seg * 512);
        }
    };
    auto stageB = [&](int t, int kh) {
        if (t >= NT) return;
        int kb = (t << 6) + (kh << 5);
        short* dst = &Bs[t & 1][kh][0];
#pragma unroll
        for (int i = 0; i < 2; i++) {
            int seg = wid * 2 + i;
            int row = seg * 16 + srw;
            gload16(Bt + (size_t)(col0 + row) * K + kb + sg * 8, dst + seg * 512);
        }
    };

    short8 af[8], bf[2];
    auto lda = [&](int d, int kh) {
#pragma unroll
        for (int m = 0; m < 8; m++) {
            int row = wr * 128 + m * 16 + t15;
            af[m] = *(short8*)(&As[d][kh][row * 32 + ce * 8]);
        }
    };
    auto ldb = [&](int d, int kh, int np) {
#pragma unroll
        for (int j = 0; j < 2; j++) {
            int row = wc * 64 + (np * 2 + j) * 16 + t15;
            bf[j] = *(short8*)(&Bs[d][kh][row * 32 + ce * 8]);
        }
    };

#define MFMA16(NP)                                                                   \
    __builtin_amdgcn_s_setprio(1);                                                   \
    _Pragma("unroll")                                                                \
    for (int m_ = 0; m_ < 8; m_++) {                                                 \
        acc[m_][(NP)*2 + 0] = __builtin_amdgcn_mfma_f32_16x16x32_bf16(               \
            af[m_], bf[0], acc[m_][(NP)*2 + 0], 0, 0, 0);                            \
        acc[m_][(NP)*2 + 1] = __builtin_amdgcn_mfma_f32_16x16x32_bf16(               \
            af[m_], bf[1], acc[m_][(NP)*2 + 1], 0, 0, 0);                            \
    }                                                                                \
    __builtin_amdgcn_s_setprio(0);

#define BARR asm volatile("s_barrier" ::: "memory")

    // prologue: stage A0(0) B0(0) A1(0) B1(0) A0(1) B0(1)
    stageA(0, 0); stageB(0, 0);
    stageA(0, 1); stageB(0, 1);
    stageA(1, 0); stageB(1, 0);
    if (NT >= 2) asm volatile("s_waitcnt vmcnt(8)" ::: "memory");
    else         asm volatile("s_waitcnt vmcnt(4)" ::: "memory");
    BARR;

    for (int t = 0; t < NT; t++) {
        int d = t & 1;
        // phase 0: (kh0, np0); stage A-kh1(t+1)
        lda(d, 0); ldb(d, 0, 0);
        stageA(t + 1, 1);
        BARR;
        MFMA16(0);
        BARR;
        // phase 1: (kh0, np1); stage B-kh1(t+1); wait1
        ldb(d, 0, 1);
        stageB(t + 1, 1);
        BARR;
        MFMA16(1);
        if (t + 1 < NT) asm volatile("s_waitcnt vmcnt(8)" ::: "memory");
        else            asm volatile("s_waitcnt vmcnt(0)" ::: "memory");
        BARR;
        // phase 2: (kh1, np0); stage A-kh0(t+2)
        lda(d, 1); ldb(d, 1, 0);
        stageA(t + 2, 0);
        BARR;
        MFMA16(0);
        BARR;
        // phase 3: (kh1, np1); stage B-kh0(t+2); wait2
        ldb(d, 1, 1);
        stageB(t + 2, 0);
        BARR;
        MFMA16(1);
        if (t + 2 < NT)      asm volatile("s_waitcnt vmcnt(8)" ::: "memory");
        else if (t + 1 < NT) asm volatile("s_waitcnt vmcnt(4)" ::: "memory");
        else                 asm volatile("s_waitcnt vmcnt(0)" ::: "memory");
        BARR;
    }

#undef MFMA16
#undef BARR

#pragma unroll
    for (int m = 0; m < 8; m++) {
#pragma unroll
        for (int n = 0; n < 4; n++) {
#pragma unroll
            for (int r = 0; r < 4; r++) {
                float v = acc[m][n][r];
                int gm2 = row0 + wr * 128 + m * 16 + t4 * 4 + r;
                int gn = col0 + wc * 64 + n * 16 + t15;
                if (EPI == 0) {
                    int part = gn >> 11, within = gn & 2047;
                    int h = within >> 7, dk = within & 127;
                    int bb = gm2 >> 11, s = gm2 & 2047;
                    int z = bb * 16 + h;
                    if (part == 0) O0[((size_t)z * 2048 + s) * 128 + dk] = f2bf(v * qscale);
                    else if (part == 1) O1[((size_t)z * 2048 + s) * 128 + dk] = f2bf(v);
                    else O2[((size_t)z * 128 + dk) * 2048 + s] = f2bf(v);  // V transposed
                } else {
                    OF[(size_t)gm2 * N + gn] = v;
                }
            }
        }
    }
}

// ---------------- causal flash attention (LDS-staged, paired-panel balanced) ----------------
__global__ __launch_bounds__(512, 4) void attn_fwd(const short* __restrict__ Q,
                                                   const short* __restrict__ Kb,
                                                   const short* __restrict__ Vt,
                                                   short* __restrict__ O) {
    __shared__ short Kls[2][64 * 128];
    __shared__ short Vls[128 * 64];
    __shared__ short Pls[8][16 * 72];
    int tid = threadIdx.x, lane = tid & 63, wid = tid >> 6;
    int bx = blockIdx.x, z = blockIdx.y;
    int pr = bx >> 1, hh = bx & 1;
    int qpan = (wid < 4) ? pr : (15 - pr);
    int t15 = lane & 15, t4 = lane >> 4;
    const short* Qh = Q + (size_t)z * 2048 * 128;
    const short* Kh = Kb + (size_t)z * 2048 * 128;
    const short* Vh = Vt + (size_t)z * 128 * 2048;
    int q0w = qpan * 128 + hh * 64 + (wid & 3) * 16;

    short8 qf[4];
    {
        const short* qrow = Qh + (size_t)(q0w + t15) * 128;
#pragma unroll
        for (int s = 0; s < 4; s++) qf[s] = *(const short8*)(qrow + s * 32 + t4 * 8);
    }

    f32x4 o[8];
#pragma unroll
    for (int st = 0; st < 8; st++) o[st] = (f32x4){0.f, 0.f, 0.f, 0.f};
    float m_r[4], l_r[4];
#pragma unroll
    for (int r = 0; r < 4; r++) { m_r[r] = -1e30f; l_r[r] = 0.f; }

    auto stageK = [&](int t, int buf) {
#pragma unroll
        for (int i = 0; i < 2; i++) {
            int seg = wid * 2 + i;
            int row = seg * 4 + t4;
            int kl = (lane & 15) ^ (row & 7);
            gload16(Kh + (size_t)(t * 64 + row) * 128 + kl * 8, &Kls[buf][seg * 512]);
        }
    };
    auto stageV = [&](int t) {
#pragma unroll
        for (int i = 0; i < 2; i++) {
            int seg = wid * 2 + i;
            int row = seg * 8 + (lane >> 3);
            int kl = (lane & 7) ^ (row & 7);
            gload16(Vh + (size_t)row * 2048 + t * 64 + kl * 8, &Vls[seg * 512]);
        }
    };

    int nt = 2 * (15 - pr) + 2;
    stageK(0, 0);
    __syncthreads();

    for (int t = 0; t < nt; t++) {
        int buf = t & 1;
        stageV(t);
        if (t + 1 < nt) stageK(t + 1, buf ^ 1);
        bool active = (t * 64 <= q0w + 15);

        if (active) {
            f32x4 sc[4];
#pragma unroll
            for (int c = 0; c < 4; c++) {
                sc[c] = (f32x4){0.f, 0.f, 0.f, 0.f};
#pragma unroll
                for (int s = 0; s < 4; s++) {
                    int row = c * 16 + t15;
                    int ck = (s * 4 + t4) ^ (row & 7);
                    short8 kf = *(short8*)(&Kls[buf][row * 128 + ck * 8]);
                    sc[c] = __builtin_amdgcn_mfma_f32_16x16x32_bf16(qf[s], kf, sc[c], 0, 0, 0);
                }
            }

            if (t * 64 + 63 > q0w) {
#pragma unroll
                for (int c = 0; c < 4; c++)
#pragma unroll
                    for (int r = 0; r < 4; r++) {
                        int kv = t * 64 + c * 16 + t15, qq = q0w + t4 * 4 + r;
                        if (kv > qq) sc[c][r] = -1e30f;
                    }
            }

            float tm[4];
#pragma unroll
            for (int r = 0; r < 4; r++)
                tm[r] = fmaxf(fmaxf(sc[0][r], sc[1][r]), fmaxf(sc[2][r], sc[3][r]));
            bool need = (tm[0] > m_r[0] + 8.f) | (tm[1] > m_r[1] + 8.f) |
                        (tm[2] > m_r[2] + 8.f) | (tm[3] > m_r[3] + 8.f);
            if (__any(need)) {
#pragma unroll
                for (int r = 0; r < 4; r++) {
#pragma unroll
                    for (int msk = 1; msk <= 8; msk <<= 1)
                        tm[r] = fmaxf(tm[r], __shfl_xor(tm[r], msk));
                    float mn = fmaxf(m_r[r], tm[r]);
                    float scf = __expf(m_r[r] - mn);
                    m_r[r] = mn;
                    l_r[r] *= scf;
#pragma unroll
                    for (int st = 0; st < 8; st++) o[st][r] *= scf;
                }
            }
#pragma unroll
            for (int r = 0; r < 4; r++) {
#pragma unroll
                for (int c = 0; c < 4; c++) {
                    float pv = __expf(sc[c][r] - m_r[r]);
                    Pls[wid][(t4 * 4 + r) * 72 + c * 16 + t15] = f2bf(pv);
                    l_r[r] += pv;
                }
            }
        }

        __syncthreads();

        if (active) {
            short8 pa[2];
#pragma unroll
            for (int s2 = 0; s2 < 2; s2++)
                pa[s2] = *(short8*)(&Pls[wid][0] + t15 * 72 + s2 * 32 + t4 * 8);
#pragma unroll
            for (int st = 0; st < 8; st++) {
#pragma unroll
                for (int s2 = 0; s2 < 2; s2++) {
                    int row = st * 16 + t15;
                    int ck = (s2 * 4 + t4) ^ (row & 7);
                    short8 vf = *(short8*)(&Vls[row * 64 + ck * 8]);
                    o[st] = __builtin_amdgcn_mfma_f32_16x16x32_bf16(pa[s2], vf, o[st], 0, 0, 0);
                }
            }
        }

        __syncthreads();
    }

#pragma unroll
    for (int r = 0; r < 4; r++)
#pragma unroll
        for (int msk = 1; msk <= 8; msk <<= 1)
            l_r[r] += __shfl_xor(l_r[r], msk);

    int b = z >> 4, h = z & 15;
#pragma unroll
    for (int st = 0; st < 8; st++)
#pragma unroll
        for (int r = 0; r < 4; r++) {
            int s = q0w + t4 * 4 + r;
            float val = o[st][r] / l_r[r];
            O[((size_t)b * 2048 + s) * 2048 + h * 128 + st * 16 + t15] = f2bf(val);
        }
}

extern "C" void kernel_launch(void* const* d_in, const int* in_sizes, int n_in,
                              void* d_out, int out_size, void* d_ws, size_t ws_size,
                              hipStream_t stream) {
    const float* x = (const float*)d_in[0];      // (4,2048,2048)
    const float* Wqkv = (const float*)d_in[1];   // (2048,6144)
    const float* Wo = (const float*)d_in[2];     // (2048,2048)

    const int B = 4, S = 2048, D = 2048, DK = 128;
    const int M = B * S;          // 8192
    const int N1 = 3 * D;         // 6144
    (void)in_sizes; (void)n_in; (void)out_size; (void)ws_size;

    char* ws = (char*)d_ws;
    size_t off = 0;
    short* x_bf = (short*)(ws + off);   off += (size_t)M * D * 2;
    short* wqkv_t = (short*)(ws + off); off += (size_t)N1 * D * 2;
    short* wo_t = (short*)(ws + off);   off += (size_t)D * D * 2;
    short* Qb = (short*)(ws + off);     off += (size_t)64 * S * DK * 2;
    short* Kb = (short*)(ws + off);     off += (size_t)64 * S * DK * 2;
    short* Vt = (short*)(ws + off);     off += (size_t)64 * S * DK * 2;
    short* Ob = (short*)(ws + off);     off += (size_t)M * D * 2;

    // 1. x -> bf16
    cvt_f32_to_bf16<<<(M * D / 4 + 255) / 256, 256, 0, stream>>>(x, x_bf, M * D / 4);
    // 2. Wqkv^T -> bf16 (N1 x D)
    transpose_to_bf16<<<dim3(D / 64, N1 / 64, 1), 256, 0, stream>>>(Wqkv, wqkv_t, D, N1);
    // 3. Wo^T -> bf16 (D x D)
    transpose_to_bf16<<<dim3(D / 64, D / 64, 1), 256, 0, stream>>>(Wo, wo_t, D, D);
    // 4. GEMM1: qkv = x @ Wqkv -> Q(scaled)/K/V^T   (256x256 8-phase, 768 blocks)
    gemm256<0><<<(M / 256) * (N1 / 256), 512, 0, stream>>>(
        x_bf, wqkv_t, M, N1, D, Qb, Kb, Vt, nullptr, 0.08838834764831845f);
    // 5. attention (paired-panel balanced, hoisted prefetch)
    attn_fwd<<<dim3(16, 64), 512, 0, stream>>>(Qb, Kb, Vt, Ob);
    // 6. GEMM2: out = O @ Wo (f32)   (256x256 8-phase, 256 blocks = 1/CU)
    gemm256<1><<<(M / 256) * (D / 256), 512, 0, stream>>>(
        Ob, wo_t, M, D, D, nullptr, nullptr, nullptr, (float*)d_out, 1.0f);
}